// Round 8
// baseline (240.608 us; speedup 1.0000x reference)
//
#include <hip/hip_runtime.h>

#define N_NODES 100000
#define N_EDGES 1600000
#define D 64

// fine buckets: 32 nodes each, 100000/32 = 3125 exactly
#define FSHIFT 5
#define FNODES 32
#define NFB 3125
#define CAPF 768            // mean 512, sigma ~22.6 -> +11.3 sigma

// coarse buckets: 2048 nodes each
#define CSHIFT 11
#define NCB 49
#define CCAP 36864          // mean 32768, +22 sigma
#define FPC 64

#define CHUNKA 2048
#define EPTA 8
#define NCHUNKA 782         // 1600000 / 2048 = 781.25 -> 782
#define CHUNKB 2048
#define EPTB 8
#define NCHUNKB 18          // CCAP / 2048

#define COLBITS 17
#define COLMASK 0x1FFFF

#define PLANE_B 1600000     // bytes per y plane: 100000 nodes * 16 B

// ws layout (bytes)
#define CCUR_OFF   0           // int[NCB]
#define FCUR_OFF   4096        // int[NFB]
#define INIT_BYTES 16640       // one memset covers ccur+fcur
#define RPTR_OFF   16640       // int[NFB*33] absolute starts + end
#define DINV_OFF   429312      // float[N_NODES]
#define Y_OFF      829440      // bf16 y, plane-major: 8 planes x 1.6 MB
#define FPAIRS_OFF 13629440    // int[NFB*CAPF]
#define SORT_OFF   23229440    // int[NFB*CAPF]; ALSO cpairs during scatA/B

typedef float fvec4 __attribute__((ext_vector_type(4)));

__device__ __forceinline__ unsigned f2bf(float f) {
    unsigned bits = __float_as_uint(f);
    return (bits + 0x7FFFu + ((bits >> 16) & 1u)) >> 16;
}

// Pass A: bucket edges by row>>11 into 49 coarse regions.
__global__ __launch_bounds__(256) void scatA_kernel(const int* __restrict__ row,
                                                    const int* __restrict__ col,
                                                    int* __restrict__ ccur,
                                                    int* __restrict__ cpairs) {
    __shared__ int lcnt[NCB];
    int t = threadIdx.x;
    int base = blockIdx.x * CHUNKA;
    if (t < NCB) lcnt[t] = 0;
    __syncthreads();
    int r[EPTA], c[EPTA], pos[EPTA];
#pragma unroll
    for (int i = 0; i < EPTA; ++i) {
        int e = base + i * 256 + t;
        if (e < N_EDGES) {
            r[i] = row[e];
            c[i] = col[e];
            pos[i] = atomicAdd(&lcnt[r[i] >> CSHIFT], 1);
        } else r[i] = -1;
    }
    __syncthreads();
    if (t < NCB) {
        int cc = lcnt[t];
        if (cc) lcnt[t] = t * CCAP + atomicAdd(&ccur[t], cc);
    }
    __syncthreads();
#pragma unroll
    for (int i = 0; i < EPTA; ++i) {
        if (r[i] >= 0) {
            int cb = r[i] >> CSHIFT;
            int rl = r[i] & ((1 << CSHIFT) - 1);
            cpairs[lcnt[cb] + pos[i]] = (rl << COLBITS) | c[i];
        }
    }
}

// Pass B: refine one coarse chunk into its 64 fine buckets.
__global__ __launch_bounds__(256) void scatB_kernel(const int* __restrict__ cpairs,
                                                    const int* __restrict__ ccur,
                                                    int* __restrict__ fcur,
                                                    int* __restrict__ fpairs) {
    __shared__ int lcnt[FPC];
    int t = threadIdx.x;
    int cb = blockIdx.x / NCHUNKB;
    int k  = blockIdx.x % NCHUNKB;
    int beg = cb * CCAP + k * CHUNKB;
    int end = cb * CCAP + ccur[cb];
    if (end > beg + CHUNKB) end = beg + CHUNKB;
    if (t < FPC) lcnt[t] = 0;
    __syncthreads();
    int pc[EPTB], pos[EPTB];
#pragma unroll
    for (int i = 0; i < EPTB; ++i) {
        int e = beg + i * 256 + t;
        if (e < end) {
            pc[i] = cpairs[e];
            pos[i] = atomicAdd(&lcnt[pc[i] >> (COLBITS + FSHIFT)], 1);
        } else pc[i] = -1;
    }
    __syncthreads();
    if (t < FPC) {
        int cc = lcnt[t];
        if (cc) {
            int fb = (cb << 6) + t;   // fine bucket id
            lcnt[t] = fb * CAPF + atomicAdd(&fcur[fb], cc);
        }
    }
    __syncthreads();
#pragma unroll
    for (int i = 0; i < EPTB; ++i) {
        if (pc[i] >= 0) {
            int fl = pc[i] >> (COLBITS + FSHIFT);
            int rl5 = (pc[i] >> COLBITS) & (FNODES - 1);
            fpairs[lcnt[fl] + pos[i]] = (rl5 << COLBITS) | (pc[i] & COLMASK);
        }
    }
}

// Per fine bucket: hist -> scan -> dinv -> node-sorted scol + rptr (done ONCE,
// consumed by 8 slice-gather blocks and xform via dinv).
__global__ __launch_bounds__(256) void binprep_kernel(
        const int* __restrict__ fpairs, const int* __restrict__ fcur,
        int* __restrict__ sorted, int* __restrict__ rptr,
        float* __restrict__ dinv) {
    __shared__ int hist[FNODES];
    __shared__ int sc[FNODES];
    __shared__ int lcur[FNODES];
    __shared__ int lds_scol[CAPF];
    int t = threadIdx.x;
    int f = blockIdx.x;
    int beg = f * CAPF;
    int cnt = fcur[f];
    if (t < FNODES) hist[t] = 0;
    __syncthreads();
    for (int k = t; k < cnt; k += 256)
        atomicAdd(&hist[fpairs[beg + k] >> COLBITS], 1);
    __syncthreads();
    if (t < FNODES) sc[t] = hist[t];
    __syncthreads();
    for (int off = 1; off < FNODES; off <<= 1) {
        int v = (t < FNODES && t >= off) ? sc[t - off] : 0;
        __syncthreads();
        if (t < FNODES) sc[t] += v;
        __syncthreads();
    }
    if (t < FNODES) {
        int start = sc[t] - hist[t];
        lcur[t] = start;
        rptr[f * 33 + t] = beg + start;
        int n = (f << FSHIFT) + t;
        dinv[n] = (hist[t] > 0) ? rsqrtf((float)hist[t]) : 0.0f;
    }
    if (t == 0) rptr[f * 33 + 32] = beg + cnt;
    __syncthreads();
    for (int k = t; k < cnt; k += 256) {
        int p = fpairs[beg + k];
        int pos = atomicAdd(&lcur[p >> COLBITS], 1);
        lds_scol[pos] = p & COLMASK;
    }
    __syncthreads();
    for (int k = t; k < cnt; k += 256)
        sorted[beg + k] = lds_scol[k];
}

// y[n] = bf16(dinv[n] * x[n] @ W^T), written PLANE-MAJOR:
// plane p (8 feats) at Y_OFF + p*PLANE_B + node*16.
__global__ __launch_bounds__(256) void xform_kernel(
        const float* __restrict__ x, const float* __restrict__ W,
        const float* __restrict__ dinv, char* __restrict__ yb) {
    __shared__ __align__(16) float XT[D * 68];   // XT[d*68 + n]
    __shared__ __align__(16) float WT[D * 68];   // WT[d*68 + j]
    int t = threadIdx.x;
    int b = blockIdx.x;
    int nb0 = b << 6;
    for (int i = t; i < D * D; i += 256) {
        int j = i >> 6, d = i & 63;
        WT[d * 68 + j] = W[i];
    }
    for (int i = t; i < 64 * D; i += 256) {
        int n = i >> 6, d = i & 63;
        int g = nb0 + n;
        XT[d * 68 + n] = (g < N_NODES) ? x[(size_t)g * D + d] : 0.0f;
    }
    __syncthreads();
    int tj = t & 15, tn = t >> 4;
    float4 a0 = {0,0,0,0}, a1 = {0,0,0,0}, a2 = {0,0,0,0}, a3 = {0,0,0,0};
#pragma unroll 8
    for (int d = 0; d < D; ++d) {
        float4 xv = *(const float4*)&XT[d * 68 + tn * 4];
        float4 wv = *(const float4*)&WT[d * 68 + tj * 4];
        a0.x = fmaf(xv.x, wv.x, a0.x); a0.y = fmaf(xv.x, wv.y, a0.y);
        a0.z = fmaf(xv.x, wv.z, a0.z); a0.w = fmaf(xv.x, wv.w, a0.w);
        a1.x = fmaf(xv.y, wv.x, a1.x); a1.y = fmaf(xv.y, wv.y, a1.y);
        a1.z = fmaf(xv.y, wv.z, a1.z); a1.w = fmaf(xv.y, wv.w, a1.w);
        a2.x = fmaf(xv.z, wv.x, a2.x); a2.y = fmaf(xv.z, wv.y, a2.y);
        a2.z = fmaf(xv.z, wv.z, a2.z); a2.w = fmaf(xv.z, wv.w, a2.w);
        a3.x = fmaf(xv.w, wv.x, a3.x); a3.y = fmaf(xv.w, wv.y, a3.y);
        a3.z = fmaf(xv.w, wv.z, a3.z); a3.w = fmaf(xv.w, wv.w, a3.w);
    }
    int p = tj >> 1, half = tj & 1;   // features jb..jb+3 live in plane p
#pragma unroll
    for (int s = 0; s < 4; ++s) {
        int g = nb0 + tn * 4 + s;
        if (g < N_NODES) {
            float scv = dinv[g];
            float4 a = (s == 0) ? a0 : (s == 1) ? a1 : (s == 2) ? a2 : a3;
            unsigned lo = f2bf(a.x * scv) | (f2bf(a.y * scv) << 16);
            unsigned hi = f2bf(a.z * scv) | (f2bf(a.w * scv) << 16);
            *(uint2*)(yb + (size_t)p * PLANE_B + (size_t)g * 16 + half * 8) =
                make_uint2(lo, hi);
        }
    }
}

// Slice gather: block = (bucket f = blk>>3, slice s = blk&7). blk%8 -> XCD
// round-robin, so slice s's 1.6 MB plane stays L2-resident on one XCD.
// Wave = 4 node-slots x 16 edge-slots; 1 uint4/lane = 1 KB/instr; no LDS.
__global__ __launch_bounds__(256) void gather_kernel(
        const int* __restrict__ sorted, const int* __restrict__ rptr,
        const float* __restrict__ dinv, const char* __restrict__ yb,
        const float* __restrict__ bias, float* __restrict__ out) {
    int blk = blockIdx.x;
    int f = blk >> 3;
    int s = blk & 7;
    int t = threadIdx.x;
    int w = t >> 6;
    int lane = t & 63;
    int ln2 = lane >> 4;   // node slot 0..3
    int g = lane & 15;     // edge slot 0..15
    const char* yp = yb + (size_t)s * PLANE_B;
    float bj[8];
    {
        float4 b0 = *(const float4*)(bias + s * 8);
        float4 b1 = *(const float4*)(bias + s * 8 + 4);
        bj[0] = b0.x; bj[1] = b0.y; bj[2] = b0.z; bj[3] = b0.w;
        bj[4] = b1.x; bj[5] = b1.y; bj[6] = b1.z; bj[7] = b1.w;
    }
    int nb0 = f << FSHIFT;
#pragma unroll
    for (int round = 0; round < 2; ++round) {
        int ln = w * 8 + round * 4 + ln2;
        int seg = rptr[f * 33 + ln];
        int deg = rptr[f * 33 + ln + 1] - seg;
        int md = deg;
        md = max(md, __shfl_xor(md, 16));
        md = max(md, __shfl_xor(md, 32));   // wave-uniform max over 4 slots
        float a[8];
#pragma unroll
        for (int i = 0; i < 8; ++i) a[i] = 0.0f;
        for (int base = 0; base < md; base += 16) {
            int o = base + g;
            if (o < deg) {
                int c = sorted[seg + o];
                uint4 v = *(const uint4*)(yp + (size_t)c * 16);
                a[0] += __uint_as_float(v.x << 16);
                a[1] += __uint_as_float(v.x & 0xffff0000u);
                a[2] += __uint_as_float(v.y << 16);
                a[3] += __uint_as_float(v.y & 0xffff0000u);
                a[4] += __uint_as_float(v.z << 16);
                a[5] += __uint_as_float(v.z & 0xffff0000u);
                a[6] += __uint_as_float(v.w << 16);
                a[7] += __uint_as_float(v.w & 0xffff0000u);
            }
        }
#pragma unroll
        for (int m = 1; m <= 8; m <<= 1) {
#pragma unroll
            for (int i = 0; i < 8; ++i)
                a[i] += __shfl_xor(a[i], m);
        }
        if (g == 0) {
            int n = nb0 + ln;
            float dv = dinv[n];
            fvec4 r0, r1;
            r0.x = fmaxf(fmaf(dv, a[0], bj[0]), 0.0f);
            r0.y = fmaxf(fmaf(dv, a[1], bj[1]), 0.0f);
            r0.z = fmaxf(fmaf(dv, a[2], bj[2]), 0.0f);
            r0.w = fmaxf(fmaf(dv, a[3], bj[3]), 0.0f);
            r1.x = fmaxf(fmaf(dv, a[4], bj[4]), 0.0f);
            r1.y = fmaxf(fmaf(dv, a[5], bj[5]), 0.0f);
            r1.z = fmaxf(fmaf(dv, a[6], bj[6]), 0.0f);
            r1.w = fmaxf(fmaf(dv, a[7], bj[7]), 0.0f);
            __builtin_nontemporal_store(r0, (fvec4*)(out + (size_t)n * D + s * 8));
            __builtin_nontemporal_store(r1, (fvec4*)(out + (size_t)n * D + s * 8 + 4));
        }
    }
}

extern "C" void kernel_launch(void* const* d_in, const int* in_sizes, int n_in,
                              void* d_out, int out_size, void* d_ws, size_t ws_size,
                              hipStream_t stream) {
    const float* x    = (const float*)d_in[0];
    const int*   eidx = (const int*)d_in[1];
    const float* W    = (const float*)d_in[2];
    const float* b    = (const float*)d_in[3];
    float* out = (float*)d_out;
    char* ws = (char*)d_ws;

    const int* row = eidx;
    const int* col = eidx + N_EDGES;

    int*   ccur   = (int*)  (ws + CCUR_OFF);
    int*   fcur   = (int*)  (ws + FCUR_OFF);
    int*   rptr   = (int*)  (ws + RPTR_OFF);
    float* dinv   = (float*)(ws + DINV_OFF);
    char*  yb     =          ws + Y_OFF;
    int*   fpairs = (int*)  (ws + FPAIRS_OFF);
    int*   sorted = (int*)  (ws + SORT_OFF);   // overlays cpairs (dead after scatB)
    int*   cpairs = (int*)  (ws + SORT_OFF);

    hipMemsetAsync(ws + CCUR_OFF, 0, INIT_BYTES, stream);
    scatA_kernel<<<NCHUNKA, 256, 0, stream>>>(row, col, ccur, cpairs);
    scatB_kernel<<<NCB * NCHUNKB, 256, 0, stream>>>(cpairs, ccur, fcur, fpairs);
    binprep_kernel<<<NFB, 256, 0, stream>>>(fpairs, fcur, sorted, rptr, dinv);
    xform_kernel<<<(N_NODES + 63) / 64, 256, 0, stream>>>(x, W, dinv, yb);
    gather_kernel<<<NFB * 8, 256, 0, stream>>>(sorted, rptr, dinv, yb, b, out);
}